// Round 7
// baseline (342.247 us; speedup 1.0000x reference)
//
#include <hip/hip_runtime.h>
#include <hip/hip_bf16.h>
#include <math.h>

constexpr int DXc = 1024;
constexpr int DZc = 1024;
constexpr int LXc = 4096;
constexpr int LZc = 4096;
constexpr int DAc = 1024;   // DATTN
constexpr int DOc = 1024;   // DOUT

typedef __attribute__((ext_vector_type(8))) short bf16x8;
typedef __attribute__((ext_vector_type(4))) float f32x4;

__device__ __forceinline__ ushort f2bf(float f) {
    __hip_bfloat16 h = __float2bfloat16(f);
    return *reinterpret_cast<ushort*>(&h);
}
__device__ __forceinline__ float bflo(unsigned u) {
    return __builtin_bit_cast(float, u << 16);
}
__device__ __forceinline__ float bfhi(unsigned u) {
    return __builtin_bit_cast(float, u & 0xffff0000u);
}

enum BiasMode { BIAS_NONE, BIAS_M, BIAS_N };

// ---------------------------------------------------------------------------
// Core 128x128xK bf16 MFMA loop (both operands K-major): acc += A.B^T tile.
// 256 threads = 4 waves (2x2), each wave 64x64 via 4x4 MFMA 16x16x32.
// global_load_lds width=16 staging, contiguous lane-order LDS (no padding).
// ---------------------------------------------------------------------------
__device__ __forceinline__ void gemm_core(
    const ushort* __restrict__ A, const ushort* __restrict__ B,
    int K, int lda, int ldb, int m0, int n0, int kbase,
    ushort* As, ushort* Bs, f32x4 (*acc)[4])
{
    constexpr int BK = 32;
    const int tid = threadIdx.x;
    const int wv  = tid >> 6;
    const int wm  = (wv >> 1) * 64;
    const int wn  = (wv & 1) * 64;
    const int ln  = tid & 63;
    const int lrow = ln & 15;
    const int quad = ln >> 4;

    const int srow = tid >> 2;
    const int sseg = (tid & 3) * 8;
    const ushort* Ag = A + (size_t)(m0 + srow) * lda + sseg + kbase;
    const ushort* Bg = B + (size_t)(n0 + srow) * ldb + sseg + kbase;
    ushort* AsW = As + wv * 512;
    ushort* BsW = Bs + wv * 512;

    for (int k0 = 0; k0 < K; k0 += BK) {
        __syncthreads();
        __builtin_amdgcn_global_load_lds(
            (const __attribute__((address_space(1))) void*)(Ag + k0),
            (__attribute__((address_space(3))) void*)(AsW), 16, 0, 0);
        __builtin_amdgcn_global_load_lds(
            (const __attribute__((address_space(1))) void*)(Ag + (size_t)64 * lda + k0),
            (__attribute__((address_space(3))) void*)(AsW + 2048), 16, 0, 0);
        __builtin_amdgcn_global_load_lds(
            (const __attribute__((address_space(1))) void*)(Bg + k0),
            (__attribute__((address_space(3))) void*)(BsW), 16, 0, 0);
        __builtin_amdgcn_global_load_lds(
            (const __attribute__((address_space(1))) void*)(Bg + (size_t)64 * ldb + k0),
            (__attribute__((address_space(3))) void*)(BsW + 2048), 16, 0, 0);
        __syncthreads();

        bf16x8 af[4], bfr[4];
        #pragma unroll
        for (int t = 0; t < 4; ++t) {
            af[t]  = *reinterpret_cast<const bf16x8*>(&As[(wm + t * 16 + lrow) * BK + quad * 8]);
            bfr[t] = *reinterpret_cast<const bf16x8*>(&Bs[(wn + t * 16 + lrow) * BK + quad * 8]);
        }
        #pragma unroll
        for (int mi = 0; mi < 4; ++mi)
            #pragma unroll
            for (int nj = 0; nj < 4; ++nj)
                acc[mi][nj] = __builtin_amdgcn_mfma_f32_16x16x32_bf16(
                    af[mi], bfr[nj], acc[mi][nj], 0, 0, 0);
    }
}

// Epilogue: optional bias + bf16 store
template<BiasMode BMODE>
__device__ __forceinline__ void epi_bias_bf16(
    f32x4 (*acc)[4], const float* __restrict__ bias,
    ushort* __restrict__ C, int ldc, int m0, int n0)
{
    const int tid = threadIdx.x;
    const int wv  = tid >> 6;
    const int wm  = (wv >> 1) * 64;
    const int wn  = (wv & 1) * 64;
    const int lrow = tid & 15;
    const int quad = (tid & 63) >> 4;
    #pragma unroll
    for (int mi = 0; mi < 4; ++mi)
        #pragma unroll
        for (int r = 0; r < 4; ++r) {
            const int m = m0 + wm + mi * 16 + quad * 4 + r;
            const float bm = (BMODE == BIAS_M) ? bias[m] : 0.0f;
            #pragma unroll
            for (int nj = 0; nj < 4; ++nj) {
                const int n = n0 + wn + nj * 16 + lrow;
                const float v = acc[mi][nj][r] + ((BMODE == BIAS_N) ? bias[n] : bm);
                C[(size_t)m * ldc + n] = f2bf(v);
            }
        }
}

// ---------------------------------------------------------------------------
// Batched projection GEMM (768 blocks): q, k, v in one dispatch.
// ---------------------------------------------------------------------------
__global__ __launch_bounds__(256)
void proj_kernel(const ushort* __restrict__ XT, const ushort* __restrict__ ZT,
                 const ushort* __restrict__ Wqb, const ushort* __restrict__ Wkb,
                 const ushort* __restrict__ Wvb,
                 const float* __restrict__ bq, const float* __restrict__ bk,
                 const float* __restrict__ bv,
                 ushort* __restrict__ qT, ushort* __restrict__ kT,
                 ushort* __restrict__ vB)
{
    __shared__ __align__(16) ushort As[128 * 32];
    __shared__ __align__(16) ushort Bs[128 * 32];
    f32x4 acc[4][4] = {};
    int b = blockIdx.x;
    if (b < 256) {
        const int m0 = (b >> 3) * 128, n0 = (b & 7) * 128;
        gemm_core(XT, Wqb, DXc, DXc, DXc, m0, n0, 0, As, Bs, acc);
        epi_bias_bf16<BIAS_N>(acc, bq, qT, DAc, m0, n0);
    } else if (b < 512) {
        b -= 256;
        const int m0 = (b >> 3) * 128, n0 = (b & 7) * 128;
        gemm_core(ZT, Wkb, DZc, DZc, DZc, m0, n0, 0, As, Bs, acc);
        epi_bias_bf16<BIAS_N>(acc, bk, kT, DAc, m0, n0);
    } else {
        b -= 512;
        const int m0 = (b >> 5) * 128, n0 = (b & 31) * 128;
        gemm_core(Wvb, ZT, DZc, DZc, DZc, m0, n0, 0, As, Bs, acc);
        epi_bias_bf16<BIAS_M>(acc, bv, vB, LZc, m0, n0);
    }
}

// Score GEMM (pure): sTb[x,z] = sum_d qT[x,d] kT[z,d]  (raw bf16 scores)
__global__ __launch_bounds__(256)
void score_kernel(const ushort* __restrict__ qT, const ushort* __restrict__ kT,
                  ushort* __restrict__ sTb)
{
    __shared__ __align__(16) ushort As[128 * 32];
    __shared__ __align__(16) ushort Bs[128 * 32];
    f32x4 acc[4][4] = {};
    const int b = blockIdx.x;
    const int m0 = (b >> 5) * 128, n0 = (b & 31) * 128;
    gemm_core(qT, kT, DAc, DAc, DAc, m0, n0, 0, As, Bs, acc);
    epi_bias_bf16<BIAS_NONE>(acc, nullptr, sTb, LZc, m0, n0);
}

// ---------------------------------------------------------------------------
// Exp + rowsum pass (one block per x-row, 4096 blocks):
//   p = mask ? exp(s/32 - 10) : 0   (bf16, in place)
//   rinv[x] = 1 / sum_z p
// No max pass needed: |s|/32 <= 32 so exp(s/32-10) <= e^22 (no overflow).
// ---------------------------------------------------------------------------
__global__ __launch_bounds__(256)
void expsum_kernel(ushort* __restrict__ sTb, const unsigned* __restrict__ bits,
                   float* __restrict__ rinv)
{
    const int x   = blockIdx.x;
    const int tid = threadIdx.x;
    ushort* row = sTb + (size_t)x * LZc;
    constexpr float scale = 1.0f / 32.0f;   // 1/sqrt(1024)

    float sum = 0.0f;
    #pragma unroll
    for (int r = 0; r < 2; ++r) {
        uint4 pk = *reinterpret_cast<uint4*>(row + (size_t)(r * 256 + tid) * 8);
        unsigned* w = reinterpret_cast<unsigned*>(&pk);
        const unsigned mb = (bits[(size_t)x * 128 + r * 64 + (tid >> 2)] >> ((tid & 3) * 8)) & 0xffu;
        #pragma unroll
        for (int j = 0; j < 4; ++j) {
            const float lo = ((mb >> (2 * j))     & 1u) ? __expf(bflo(w[j]) * scale - 10.0f) : 0.0f;
            const float hi = ((mb >> (2 * j + 1)) & 1u) ? __expf(bfhi(w[j]) * scale - 10.0f) : 0.0f;
            const unsigned l = f2bf(lo), h = f2bf(hi);
            w[j] = l | (h << 16);
            sum += bflo(l) + bflo(h);   // sum exactly what we stored (BUGFIX: was bflo(h<<16)==0)
        }
        *reinterpret_cast<uint4*>(row + (size_t)(r * 256 + tid) * 8) = pk;
    }
    __shared__ float redsum[4];
    #pragma unroll
    for (int off = 32; off > 0; off >>= 1)
        sum += __shfl_down(sum, off, 64);
    if ((tid & 63) == 0) redsum[tid >> 6] = sum;
    __syncthreads();
    if (tid == 0) {
        const float s = redsum[0] + redsum[1] + redsum[2] + redsum[3];
        rinv[x] = 1.0f / fmaxf(s, 1e-35f);
    }
}

// ---------------------------------------------------------------------------
// Out GEMM split-K=4, normalized atomic accumulation into out (pre-zeroed):
//   out[o,x] += (sum_{z in split} v[o,z] p[x,z]) * rinv[x]
// ---------------------------------------------------------------------------
__global__ __launch_bounds__(256)
void out_kernel(const ushort* __restrict__ vB, const ushort* __restrict__ sTb,
                const float* __restrict__ rinv, float* __restrict__ out)
{
    __shared__ __align__(16) ushort As[128 * 32];
    __shared__ __align__(16) ushort Bs[128 * 32];
    f32x4 acc[4][4] = {};
    const int m0 = blockIdx.y * 128, n0 = blockIdx.x * 128;
    gemm_core(vB, sTb, LZc / 4, LZc, LZc, m0, n0, blockIdx.z * (LZc / 4), As, Bs, acc);

    const int tid = threadIdx.x;
    const int wv  = tid >> 6;
    const int wm  = (wv >> 1) * 64;
    const int wn  = (wv & 1) * 64;
    const int lrow = tid & 15;
    const int quad = (tid & 63) >> 4;

    float inv[4];
    int nn[4];
    #pragma unroll
    for (int nj = 0; nj < 4; ++nj) {
        nn[nj]  = n0 + wn + nj * 16 + lrow;
        inv[nj] = rinv[nn[nj]];
    }
    #pragma unroll
    for (int mi = 0; mi < 4; ++mi)
        #pragma unroll
        for (int r = 0; r < 4; ++r) {
            const int m = m0 + wm + mi * 16 + quad * 4 + r;
            #pragma unroll
            for (int nj = 0; nj < 4; ++nj)
                atomicAdd(&out[(size_t)m * LXc + nn[nj]], acc[mi][nj][r] * inv[nj]);
        }
}

// ---------------------------------------------------------------------------
// Prep: X->XT bf16 transpose, Z->ZT, W converts, mask -> bitsT[x][z/32].
// ---------------------------------------------------------------------------
__global__ __launch_bounds__(256)
void prep_kernel(const float* __restrict__ X, const float* __restrict__ Z,
                 const float* __restrict__ Wq, const float* __restrict__ Wk,
                 const float* __restrict__ Wv, const int* __restrict__ mask,
                 ushort* __restrict__ XT, ushort* __restrict__ ZT,
                 ushort* __restrict__ Wqb, ushort* __restrict__ Wkb,
                 ushort* __restrict__ Wvb, unsigned* __restrict__ bits)
{
    __shared__ float tile[32][33];
    const int tid = threadIdx.x;
    int b = blockIdx.x;

    if (b < 8192) {
        const float* in  = (b < 4096) ? X : Z;
        ushort*      out = (b < 4096) ? XT : ZT;
        const int local = b & 4095;
        const int c0 = (local & 127) * 32, r0 = (local >> 7) * 32;
        const int tx = tid & 31, ty = tid >> 5;
        #pragma unroll
        for (int i = 0; i < 32; i += 8)
            tile[ty + i][tx] = in[(size_t)(r0 + ty + i) * LXc + c0 + tx];
        __syncthreads();
        #pragma unroll
        for (int i = 0; i < 32; i += 8)
            out[(size_t)(c0 + ty + i) * DXc + r0 + tx] = f2bf(tile[tx][ty + i]);
        return;
    }
    if (b < 11264) {
        b -= 8192;
        const float* in  = (b < 1024) ? Wq : (b < 2048) ? Wk : Wv;
        ushort*      out = (b < 1024) ? Wqb : (b < 2048) ? Wkb : Wvb;
        const size_t i = ((size_t)(b & 1023) * 256 + tid) * 4;
        float4 f = *reinterpret_cast<const float4*>(in + i);
        ushort4 u;
        u.x = f2bf(f.x); u.y = f2bf(f.y); u.z = f2bf(f.z); u.w = f2bf(f.w);
        *reinterpret_cast<ushort4*>(out + i) = u;
        return;
    }
    b -= 11264;
    const int xb = b & 15, zb = b >> 4;
    const int x  = xb * 256 + tid;
    const int z0 = zb * 32;
    unsigned w = 0;
    #pragma unroll 8
    for (int i = 0; i < 32; ++i)
        w |= (mask[(size_t)(z0 + i) * LXc + x] != 0 ? 1u : 0u) << i;
    bits[(size_t)x * (LZc / 32) + zb] = w;
}

// ---------------------------------------------------------------------------
extern "C" void kernel_launch(void* const* d_in, const int* in_sizes, int n_in,
                              void* d_out, int out_size, void* d_ws, size_t ws_size,
                              hipStream_t stream)
{
    const float* X    = (const float*)d_in[0];
    const float* Z    = (const float*)d_in[1];
    const int*   mask = (const int*)  d_in[2];
    const float* Wq   = (const float*)d_in[3];
    const float* bq   = (const float*)d_in[4];
    const float* Wk   = (const float*)d_in[5];
    const float* bk   = (const float*)d_in[6];
    const float* Wv   = (const float*)d_in[7];
    const float* bv   = (const float*)d_in[8];
    float* out = (float*)d_out;

    // ws layout (~80 MB), no overlays
    char* ws = (char*)d_ws;
    ushort*   XT   = (ushort*)(ws);                    // 8 MB
    ushort*   ZT   = (ushort*)(ws + ( 8ull << 20));    // 8 MB
    ushort*   Wqb  = (ushort*)(ws + (16ull << 20));    // 2 MB
    ushort*   Wkb  = (ushort*)(ws + (18ull << 20));    // 2 MB
    ushort*   Wvb  = (ushort*)(ws + (20ull << 20));    // 2 MB
    ushort*   qT   = (ushort*)(ws + (22ull << 20));    // 8 MB
    ushort*   kT   = (ushort*)(ws + (30ull << 20));    // 8 MB
    ushort*   vB   = (ushort*)(ws + (38ull << 20));    // 8 MB
    ushort*   sTb  = (ushort*)(ws + (46ull << 20));    // 32 MB
    unsigned* bits = (unsigned*)(ws + (78ull << 20));  // 2 MB
    float*    rinv = (float*)  (ws + (80ull << 20));   // 16 KB

    hipMemsetAsync(out, 0, (size_t)DOc * LXc * sizeof(float), stream);
    prep_kernel<<<dim3(13312), 256, 0, stream>>>(X, Z, Wq, Wk, Wv, mask,
                                                 XT, ZT, Wqb, Wkb, Wvb, bits);
    proj_kernel<<<dim3(768), 256, 0, stream>>>(XT, ZT, Wqb, Wkb, Wvb,
                                               bq, bk, bv, qT, kT, vB);
    score_kernel<<<dim3(1024), 256, 0, stream>>>(qT, kT, sTb);
    expsum_kernel<<<dim3(LXc), 256, 0, stream>>>(sTb, bits, rinv);
    out_kernel<<<dim3(32, 8, 4), 256, 0, stream>>>(vB, sTb, rinv, out);
}